// Round 1
// baseline (2797.794 us; speedup 1.0000x reference)
//
#include <hip/hip_runtime.h>

constexpr int Bn = 8, Nn = 1024, Cn = 768, Hn = 12, Dn = 64;
constexpr int Mn = Bn * Nn;          // 8192
constexpr int K3 = 3 * Cn;           // 2304

__device__ __forceinline__ unsigned toOrd(float f) {
  unsigned u = __float_as_uint(f);
  return (u & 0x80000000u) ? ~u : (u | 0x80000000u);
}

// ---------------- QKV GEMM: qkv = x @ qkv_w^T + b, scattered to q/k/v (B,H,N,d)
__global__ __launch_bounds__(256) void qkv_gemm(
    const float* __restrict__ X, const float* __restrict__ Wm,
    const float* __restrict__ bias,
    float* __restrict__ qb, float* __restrict__ kb, float* __restrict__ vb)
{
  constexpr int K = Cn, BK = 16, PAD = 68;
  __shared__ float As[BK][PAD];
  __shared__ float Bs[BK][PAD];
  int t = threadIdx.x;
  int tx = t & 15, ty = t >> 4;
  int mt = blockIdx.x & 127;        // 128 m-tiles
  int nt = blockIdx.x >> 7;         // 36 n-tiles
  int m0 = mt * 64, n0 = nt * 64;
  int lrow = t >> 2;                // 0..63
  int lk = (t & 3) * 4;             // 0,4,8,12
  const float* Arow = X + (size_t)(m0 + lrow) * K + lk;
  const float* Brow = Wm + (size_t)(n0 + lrow) * K + lk;
  float acc[4][4] = {};
  for (int k0 = 0; k0 < K; k0 += BK) {
    float4 a = *(const float4*)(Arow + k0);
    float4 b = *(const float4*)(Brow + k0);
    __syncthreads();
    As[lk+0][lrow] = a.x; As[lk+1][lrow] = a.y; As[lk+2][lrow] = a.z; As[lk+3][lrow] = a.w;
    Bs[lk+0][lrow] = b.x; Bs[lk+1][lrow] = b.y; Bs[lk+2][lrow] = b.z; Bs[lk+3][lrow] = b.w;
    __syncthreads();
#pragma unroll
    for (int kk = 0; kk < BK; ++kk) {
      float4 a4 = *(const float4*)(&As[kk][ty*4]);
      float4 b4 = *(const float4*)(&Bs[kk][tx*4]);
      float av[4] = {a4.x, a4.y, a4.z, a4.w};
      float bv[4] = {b4.x, b4.y, b4.z, b4.w};
#pragma unroll
      for (int i = 0; i < 4; ++i)
#pragma unroll
        for (int j = 0; j < 4; ++j) acc[i][j] = fmaf(av[i], bv[j], acc[i][j]);
    }
  }
  // epilogue: scatter. All 64 cols of this tile share one (which, h) group.
  int c0 = n0 + tx*4;
  int which = c0 / Cn;
  int rem = c0 - which*Cn;
  int h = rem >> 6, dd = rem & 63;
  float* dst = which == 0 ? qb : (which == 1 ? kb : vb);
  float sc = which == 0 ? 0.125f : 1.0f;   // q pre-scaled by d^-0.5
  float4 bsv = *(const float4*)(bias + c0);
#pragma unroll
  for (int i = 0; i < 4; ++i) {
    int m = m0 + ty*4 + i;
    int bbi = m >> 10, n = m & 1023;
    float4 o;
    o.x = (acc[i][0] + bsv.x) * sc;
    o.y = (acc[i][1] + bsv.y) * sc;
    o.z = (acc[i][2] + bsv.z) * sc;
    o.w = (acc[i][3] + bsv.w) * sc;
    *(float4*)(dst + (((size_t)(bbi*Hn + h))*Nn + n)*Dn + dd) = o;
  }
}

// ---------------- Proj GEMM: out = att @ proj_w^T + b -----------------------
__global__ __launch_bounds__(256) void proj_gemm(
    const float* __restrict__ X, const float* __restrict__ Wm,
    const float* __restrict__ bias, float* __restrict__ Out)
{
  constexpr int K = Cn, BK = 16, PAD = 68;
  __shared__ float As[BK][PAD];
  __shared__ float Bs[BK][PAD];
  int t = threadIdx.x;
  int tx = t & 15, ty = t >> 4;
  int mt = blockIdx.x & 127;
  int nt = blockIdx.x >> 7;         // 12 n-tiles
  int m0 = mt * 64, n0 = nt * 64;
  int lrow = t >> 2;
  int lk = (t & 3) * 4;
  const float* Arow = X + (size_t)(m0 + lrow) * K + lk;
  const float* Brow = Wm + (size_t)(n0 + lrow) * K + lk;
  float acc[4][4] = {};
  for (int k0 = 0; k0 < K; k0 += BK) {
    float4 a = *(const float4*)(Arow + k0);
    float4 b = *(const float4*)(Brow + k0);
    __syncthreads();
    As[lk+0][lrow] = a.x; As[lk+1][lrow] = a.y; As[lk+2][lrow] = a.z; As[lk+3][lrow] = a.w;
    Bs[lk+0][lrow] = b.x; Bs[lk+1][lrow] = b.y; Bs[lk+2][lrow] = b.z; Bs[lk+3][lrow] = b.w;
    __syncthreads();
#pragma unroll
    for (int kk = 0; kk < BK; ++kk) {
      float4 a4 = *(const float4*)(&As[kk][ty*4]);
      float4 b4 = *(const float4*)(&Bs[kk][tx*4]);
      float av[4] = {a4.x, a4.y, a4.z, a4.w};
      float bv[4] = {b4.x, b4.y, b4.z, b4.w};
#pragma unroll
      for (int i = 0; i < 4; ++i)
#pragma unroll
        for (int j = 0; j < 4; ++j) acc[i][j] = fmaf(av[i], bv[j], acc[i][j]);
    }
  }
  int c0 = n0 + tx*4;
  float4 bsv = *(const float4*)(bias + c0);
#pragma unroll
  for (int i = 0; i < 4; ++i) {
    int m = m0 + ty*4 + i;
    float4 o;
    o.x = acc[i][0] + bsv.x;
    o.y = acc[i][1] + bsv.y;
    o.z = acc[i][2] + bsv.z;
    o.w = acc[i][3] + bsv.w;
    *(float4*)(Out + (size_t)m*Cn + c0) = o;
  }
}

// ---------------- Attention: scores + exact top-k + softmax + PV ------------
// One block = (b,h) x 8 q-rows. 256 threads.
__global__ __launch_bounds__(256) void attn_kernel(
    const float* __restrict__ qB, const float* __restrict__ kB,
    const float* __restrict__ vB, const int* __restrict__ kptr,
    float* __restrict__ out)
{
  constexpr int G = 8, CAP = 96;
  __shared__ float  Ws[G][1024];     // scores -> weights (in place)
  __shared__ float4 Qs[G][16];
  __shared__ int    hist[G][256];
  __shared__ int    PartI[G][32];
  __shared__ float  PartF[G][32];
  __shared__ int    selB[G], selAbove[G], cnt[G];
  __shared__ float  rowmax[G], rowZ[G];
  __shared__ int    widx[G][CAP];
  __shared__ float  wval[G][CAP];

  int t = threadIdx.x;
  int bh = blockIdx.x >> 7;          // 0..95  (b*12+h)
  int qg = blockIdx.x & 127;
  int qbase = qg * G;
  const float* Kbh = kB + (size_t)bh * Nn * Dn;
  const float* Vbh = vB + (size_t)bh * Nn * Dn;
  const float* Qbh = qB + (size_t)bh * Nn * Dn;

  // stage Q rows (q already scaled by 1/8)
  for (int i = t; i < G*16; i += 256) {
    int r = i >> 4, d4 = i & 15;
    Qs[r][d4] = ((const float4*)(Qbh + (size_t)(qbase + r) * Dn))[d4];
  }
  if (t < G) cnt[t] = 0;
  __syncthreads();

  // ---- scores: each thread 4 keys (2 in flight), all G rows ----
  for (int pass = 0; pass < 2; ++pass) {
    int j0 = t + pass*512;
    int j1 = j0 + 256;
    const float4* K0 = (const float4*)(Kbh + (size_t)j0 * Dn);
    const float4* K1 = (const float4*)(Kbh + (size_t)j1 * Dn);
    float acc0[G] = {}, acc1[G] = {};
#pragma unroll
    for (int d4 = 0; d4 < 16; ++d4) {
      float4 k0 = K0[d4], k1 = K1[d4];
#pragma unroll
      for (int r = 0; r < G; ++r) {
        float4 q4 = Qs[r][d4];   // uniform LDS read -> broadcast
        acc0[r] = fmaf(q4.x,k0.x, fmaf(q4.y,k0.y, fmaf(q4.z,k0.z, fmaf(q4.w,k0.w, acc0[r]))));
        acc1[r] = fmaf(q4.x,k1.x, fmaf(q4.y,k1.y, fmaf(q4.z,k1.z, fmaf(q4.w,k1.w, acc1[r]))));
      }
    }
#pragma unroll
    for (int r = 0; r < G; ++r) { Ws[r][j0] = acc0[r]; Ws[r][j1] = acc1[r]; }
  }
  __syncthreads();

  // ---- exact k-th largest via 4x8-bit radix select (32 threads per row) ----
  int kval = *kptr;
  int r = t >> 5, l = t & 31;
  unsigned thr_u = 0u;
  bool doSel = (kval > 0 && kval < Nn);   // block-uniform
  if (doSel) {
    unsigned prefix = 0u, pmask = 0u;
    int kk = kval;
    for (int pass = 0; pass < 4; ++pass) {
      int shift = 24 - 8*pass;
      for (int bI = l; bI < 256; bI += 32) hist[r][bI] = 0;
      __syncthreads();
      for (int j = l; j < 1024; j += 32) {
        unsigned u = toOrd(Ws[r][j]);
        if ((u & pmask) == prefix) atomicAdd(&hist[r][(u >> shift) & 255], 1);
      }
      __syncthreads();
      int base = l*8, part = 0;
#pragma unroll
      for (int i = 0; i < 8; ++i) part += hist[r][base+i];
      PartI[r][l] = part;
      __syncthreads();
      int run = 0;
      for (int i = l+1; i < 32; ++i) run += PartI[r][i];
#pragma unroll
      for (int i = 7; i >= 0; --i) { run += hist[r][base+i]; hist[r][base+i] = run; }
      __syncthreads();
#pragma unroll
      for (int i = 0; i < 8; ++i) {
        int bI = base + i;
        int Sb = hist[r][bI];
        int Sb1 = (bI < 255) ? hist[r][bI+1] : 0;
        if (Sb >= kk && Sb1 < kk) { selB[r] = bI; selAbove[r] = Sb1; }
      }
      __syncthreads();
      prefix |= (unsigned)selB[r] << shift;
      pmask  |= 0xFFu << shift;
      kk     -= selAbove[r];
      __syncthreads();
    }
    thr_u = prefix;   // exact bit pattern of the k-th largest score
  }

  // ---- row max ----
  float lmax = -3.4e38f;
  for (int j = l; j < 1024; j += 32) lmax = fmaxf(lmax, Ws[r][j]);
  PartF[r][l] = lmax;
  __syncthreads();
  if (l == 0) {
    float mm = PartF[r][0];
    for (int i = 1; i < 32; ++i) mm = fmaxf(mm, PartF[r][i]);
    rowmax[r] = mm;
  }
  __syncthreads();
  float mrow = rowmax[r];

  // ---- weights + compaction ----
  float lZ = 0.f;
  for (int j = l; j < 1024; j += 32) {
    float s = Ws[r][j];
    float w = 0.f;
    if (!doSel || toOrd(s) >= thr_u) {
      w = __expf(s - mrow);
      int pos = atomicAdd(&cnt[r], 1);
      if (pos < CAP) { widx[r][pos] = j; wval[r][pos] = w; }
    }
    Ws[r][j] = w;
    lZ += w;
  }
  PartF[r][l] = lZ;
  __syncthreads();
  if (l == 0) {
    float z = 0.f;
    for (int i = 0; i < 32; ++i) z += PartF[r][i];
    rowZ[r] = z;
  }
  __syncthreads();

  // ---- PV: 32 threads per row, float2 per thread over d ----
  int count = cnt[r];
  float zinv = 1.0f / rowZ[r];
  float2 acc2; acc2.x = 0.f; acc2.y = 0.f;
  const float2* V2 = (const float2*)Vbh;
  if (count <= CAP) {
    for (int i = 0; i < count; ++i) {
      int j = widx[r][i];
      float w = wval[r][i];
      float2 v2 = V2[(size_t)j*32 + l];
      acc2.x = fmaf(w, v2.x, acc2.x);
      acc2.y = fmaf(w, v2.y, acc2.y);
    }
  } else {  // tie overflow fallback (rare): walk all keys
    for (int j = 0; j < 1024; ++j) {
      float w = Ws[r][j];
      if (w != 0.f) {
        float2 v2 = V2[(size_t)j*32 + l];
        acc2.x = fmaf(w, v2.x, acc2.x);
        acc2.y = fmaf(w, v2.y, acc2.y);
      }
    }
  }
  int b = bh / Hn, h = bh - b*Hn;
  float2 o; o.x = acc2.x * zinv; o.y = acc2.y * zinv;
  ((float2*)(out + ((size_t)(b*Nn + qbase + r))*Cn + h*Dn))[l] = o;
}

extern "C" void kernel_launch(void* const* d_in, const int* in_sizes, int n_in,
                              void* d_out, int out_size, void* d_ws, size_t ws_size,
                              hipStream_t stream) {
  const float* x      = (const float*)d_in[0];
  const float* qkv_w  = (const float*)d_in[1];
  const float* qkv_b  = (const float*)d_in[2];
  const float* proj_w = (const float*)d_in[3];
  const float* proj_b = (const float*)d_in[4];
  const int*   kptr   = (const int*)d_in[5];

  float* ws  = (float*)d_ws;
  const size_t sz = (size_t)Bn * Hn * Nn * Dn;   // 6291456 elements
  float* qbuf = ws;
  float* kbuf = ws + sz;
  float* vbuf = ws + 2*sz;
  float* att  = ws + 3*sz;                       // (B,N,C)
  float* outp = (float*)d_out;

  qkv_gemm<<<dim3(36*128), 256, 0, stream>>>(x, qkv_w, qkv_b, qbuf, kbuf, vbuf);
  attn_kernel<<<dim3(Bn*Hn*(Nn/8)), 256, 0, stream>>>(qbuf, kbuf, vbuf, kptr, att);
  proj_gemm<<<dim3(12*128), 256, 0, stream>>>(att, proj_w, proj_b, outp);
}

// Round 2
// 1556.758 us; speedup vs baseline: 1.7972x; 1.7972x over previous
//
#include <hip/hip_runtime.h>

constexpr int Bn = 8, Nn = 1024, Cn = 768, Hn = 12, Dn = 64;

__device__ __forceinline__ unsigned toOrd(float f) {
  unsigned u = __float_as_uint(f);
  return (u & 0x80000000u) ? ~u : (u | 0x80000000u);
}

// ---------------- QKV GEMM: qkv = x @ qkv_w^T + b, scattered to q/k/v (B,H,N,d)
__global__ __launch_bounds__(256) void qkv_gemm(
    const float* __restrict__ X, const float* __restrict__ Wm,
    const float* __restrict__ bias,
    float* __restrict__ qb, float* __restrict__ kb, float* __restrict__ vb)
{
  constexpr int K = Cn, BK = 16, PAD = 68;
  __shared__ float As[BK][PAD];
  __shared__ float Bs[BK][PAD];
  int t = threadIdx.x;
  int tx = t & 15, ty = t >> 4;
  int mt = blockIdx.x & 127;        // 128 m-tiles
  int nt = blockIdx.x >> 7;         // 36 n-tiles
  int m0 = mt * 64, n0 = nt * 64;
  int lrow = t >> 2;                // 0..63
  int lk = (t & 3) * 4;             // 0,4,8,12
  const float* Arow = X + (size_t)(m0 + lrow) * K + lk;
  const float* Brow = Wm + (size_t)(n0 + lrow) * K + lk;
  float acc[4][4] = {};
  for (int k0 = 0; k0 < K; k0 += BK) {
    float4 a = *(const float4*)(Arow + k0);
    float4 b = *(const float4*)(Brow + k0);
    __syncthreads();
    As[lk+0][lrow] = a.x; As[lk+1][lrow] = a.y; As[lk+2][lrow] = a.z; As[lk+3][lrow] = a.w;
    Bs[lk+0][lrow] = b.x; Bs[lk+1][lrow] = b.y; Bs[lk+2][lrow] = b.z; Bs[lk+3][lrow] = b.w;
    __syncthreads();
#pragma unroll
    for (int kk = 0; kk < BK; ++kk) {
      float4 a4 = *(const float4*)(&As[kk][ty*4]);
      float4 b4 = *(const float4*)(&Bs[kk][tx*4]);
      float av[4] = {a4.x, a4.y, a4.z, a4.w};
      float bv[4] = {b4.x, b4.y, b4.z, b4.w};
#pragma unroll
      for (int i = 0; i < 4; ++i)
#pragma unroll
        for (int j = 0; j < 4; ++j) acc[i][j] = fmaf(av[i], bv[j], acc[i][j]);
    }
  }
  int c0 = n0 + tx*4;
  int which = c0 / Cn;
  int rem = c0 - which*Cn;
  int h = rem >> 6, dd = rem & 63;
  float* dst = which == 0 ? qb : (which == 1 ? kb : vb);
  float sc = which == 0 ? 0.125f : 1.0f;   // q pre-scaled by d^-0.5
  float4 bsv = *(const float4*)(bias + c0);
#pragma unroll
  for (int i = 0; i < 4; ++i) {
    int m = m0 + ty*4 + i;
    int bbi = m >> 10, n = m & 1023;
    float4 o;
    o.x = (acc[i][0] + bsv.x) * sc;
    o.y = (acc[i][1] + bsv.y) * sc;
    o.z = (acc[i][2] + bsv.z) * sc;
    o.w = (acc[i][3] + bsv.w) * sc;
    *(float4*)(dst + (((size_t)(bbi*Hn + h))*Nn + n)*Dn + dd) = o;
  }
}

// ---------------- Proj GEMM: out = att @ proj_w^T + b -----------------------
__global__ __launch_bounds__(256) void proj_gemm(
    const float* __restrict__ X, const float* __restrict__ Wm,
    const float* __restrict__ bias, float* __restrict__ Out)
{
  constexpr int K = Cn, BK = 16, PAD = 68;
  __shared__ float As[BK][PAD];
  __shared__ float Bs[BK][PAD];
  int t = threadIdx.x;
  int tx = t & 15, ty = t >> 4;
  int mt = blockIdx.x & 127;
  int nt = blockIdx.x >> 7;         // 12 n-tiles
  int m0 = mt * 64, n0 = nt * 64;
  int lrow = t >> 2;
  int lk = (t & 3) * 4;
  const float* Arow = X + (size_t)(m0 + lrow) * K + lk;
  const float* Brow = Wm + (size_t)(n0 + lrow) * K + lk;
  float acc[4][4] = {};
  for (int k0 = 0; k0 < K; k0 += BK) {
    float4 a = *(const float4*)(Arow + k0);
    float4 b = *(const float4*)(Brow + k0);
    __syncthreads();
    As[lk+0][lrow] = a.x; As[lk+1][lrow] = a.y; As[lk+2][lrow] = a.z; As[lk+3][lrow] = a.w;
    Bs[lk+0][lrow] = b.x; Bs[lk+1][lrow] = b.y; Bs[lk+2][lrow] = b.z; Bs[lk+3][lrow] = b.w;
    __syncthreads();
#pragma unroll
    for (int kk = 0; kk < BK; ++kk) {
      float4 a4 = *(const float4*)(&As[kk][ty*4]);
      float4 b4 = *(const float4*)(&Bs[kk][tx*4]);
      float av[4] = {a4.x, a4.y, a4.z, a4.w};
      float bv[4] = {b4.x, b4.y, b4.z, b4.w};
#pragma unroll
      for (int i = 0; i < 4; ++i)
#pragma unroll
        for (int j = 0; j < 4; ++j) acc[i][j] = fmaf(av[i], bv[j], acc[i][j]);
    }
  }
  int c0 = n0 + tx*4;
  float4 bsv = *(const float4*)(bias + c0);
#pragma unroll
  for (int i = 0; i < 4; ++i) {
    int m = m0 + ty*4 + i;
    float4 o;
    o.x = acc[i][0] + bsv.x;
    o.y = acc[i][1] + bsv.y;
    o.z = acc[i][2] + bsv.z;
    o.w = acc[i][3] + bsv.w;
    *(float4*)(Out + (size_t)m*Cn + c0) = o;
  }
}

// ---------------- Attention: scores + wave-private exact top-k + softmax + PV
// One block = (b,h) x 8 q-rows, 512 threads = 8 waves; wave w owns row w.
__global__ __launch_bounds__(512, 4) void attn_kernel(
    const float* __restrict__ qB, const float* __restrict__ kB,
    const float* __restrict__ vB, const int* __restrict__ kptr,
    float* __restrict__ out)
{
  constexpr int G = 8, CAP = 160;
  __shared__ float  Ws[G][1024];     // scores (32 KB)
  __shared__ float4 Qs[G][16];       // 2 KB
  __shared__ int    widx[G][CAP];    // compacted survivor indices
  __shared__ float  wvalS[G][CAP];   // compacted survivor weights

  int t = threadIdx.x;
  int bh = blockIdx.x >> 7;          // 0..95  (b*12+h)
  int qg = blockIdx.x & 127;
  int qbase = qg * G;
  const float* Kbh = kB + (size_t)bh * Nn * Dn;
  const float* Vbh = vB + (size_t)bh * Nn * Dn;
  const float* Qbh = qB + (size_t)bh * Nn * Dn;

  // stage Q rows (q already scaled by 1/8)
  for (int i = t; i < G*16; i += 512) {
    int r = i >> 4, d4 = i & 15;
    Qs[r][d4] = ((const float4*)(Qbh + (size_t)(qbase + r) * Dn))[d4];
  }
  __syncthreads();

  // ---- scores: each thread 2 keys (j = t, t+512), all 8 rows ----
  {
    const float4* K0 = (const float4*)(Kbh + (size_t)t * Dn);
    const float4* K1 = (const float4*)(Kbh + (size_t)(t + 512) * Dn);
    float acc0[G] = {}, acc1[G] = {};
#pragma unroll
    for (int d4 = 0; d4 < 16; ++d4) {
      float4 k0 = K0[d4], k1 = K1[d4];
#pragma unroll
      for (int r = 0; r < G; ++r) {
        float4 q4 = Qs[r][d4];   // uniform LDS read -> broadcast
        acc0[r] = fmaf(q4.x,k0.x, fmaf(q4.y,k0.y, fmaf(q4.z,k0.z, fmaf(q4.w,k0.w, acc0[r]))));
        acc1[r] = fmaf(q4.x,k1.x, fmaf(q4.y,k1.y, fmaf(q4.z,k1.z, fmaf(q4.w,k1.w, acc1[r]))));
      }
    }
#pragma unroll
    for (int r = 0; r < G; ++r) { Ws[r][t] = acc0[r]; Ws[r][t + 512] = acc1[r]; }
  }
  __syncthreads();

  // ---- wave-private: row w, 16 scores per lane (j = lane + 64*i) ----
  int w = t >> 6, lane = t & 63;
  float f[16];
  unsigned u[16];
#pragma unroll
  for (int i = 0; i < 16; ++i) {
    f[i] = Ws[w][lane + 64*i];     // stride-64: 2-way bank alias (free)
    u[i] = toOrd(f[i]);
  }

  // row max (for softmax)
  float m = f[0];
#pragma unroll
  for (int i = 1; i < 16; ++i) m = fmaxf(m, f[i]);
#pragma unroll
  for (int off = 32; off; off >>= 1) m = fmaxf(m, __shfl_xor(m, off));

  // ---- exact k-th largest via 32-step bisection on ordinal bits ----
  int kval = *kptr;
  bool doSel = (kval > 0 && kval < Nn);   // uniform
  unsigned thr = 0u;                      // thr=0 keeps everything
  if (doSel) {
    unsigned res = 0u;
    for (int b = 31; b >= 0; --b) {
      unsigned cand = res | (1u << b);
      int c = 0;
#pragma unroll
      for (int i = 0; i < 16; ++i) c += (u[i] >= cand) ? 1 : 0;
#pragma unroll
      for (int off = 32; off; off >>= 1) c += __shfl_xor(c, off);
      if (c >= kval) res = cand;          // c uniform across wave
    }
    thr = res;   // exact bit pattern of the k-th largest score
  }

  // ---- weights + ballot compaction + Z ----
  float Zl = 0.f;
  int cnt = 0;
#pragma unroll
  for (int i = 0; i < 16; ++i) {
    bool keep = (u[i] >= thr);
    unsigned long long msk = __ballot(keep);
    if (keep) {
      int pos = cnt + __popcll(msk & ((1ull << lane) - 1ull));
      if (pos < CAP) {
        float wgt = __expf(f[i] - m);
        widx[w][pos] = lane + 64*i;
        wvalS[w][pos] = wgt;
        Zl += wgt;
      }
    }
    cnt += __popcll(msk);
  }
  if (cnt > CAP) cnt = CAP;
#pragma unroll
  for (int off = 32; off; off >>= 1) Zl += __shfl_xor(Zl, off);
  __syncthreads();   // safety: make wave-local LDS writes visible before reads

  // ---- PV: lane = output dim, survivors broadcast from LDS ----
  float acc = 0.f;
  int i = 0;
  for (; i + 4 <= cnt; i += 4) {
    int j0 = widx[w][i],   j1 = widx[w][i+1];
    int j2 = widx[w][i+2], j3 = widx[w][i+3];
    float w0 = wvalS[w][i],   w1 = wvalS[w][i+1];
    float w2 = wvalS[w][i+2], w3 = wvalS[w][i+3];
    float v0 = Vbh[(size_t)j0*Dn + lane];
    float v1 = Vbh[(size_t)j1*Dn + lane];
    float v2 = Vbh[(size_t)j2*Dn + lane];
    float v3 = Vbh[(size_t)j3*Dn + lane];
    acc = fmaf(w0, v0, acc);
    acc = fmaf(w1, v1, acc);
    acc = fmaf(w2, v2, acc);
    acc = fmaf(w3, v3, acc);
  }
  for (; i < cnt; ++i)
    acc = fmaf(wvalS[w][i], Vbh[(size_t)widx[w][i]*Dn + lane], acc);

  int b = bh / Hn, h = bh - b*Hn;
  out[((size_t)(b*Nn + qbase + w))*Cn + h*Dn + lane] = acc * (1.0f / Zl);
}

extern "C" void kernel_launch(void* const* d_in, const int* in_sizes, int n_in,
                              void* d_out, int out_size, void* d_ws, size_t ws_size,
                              hipStream_t stream) {
  const float* x      = (const float*)d_in[0];
  const float* qkv_w  = (const float*)d_in[1];
  const float* qkv_b  = (const float*)d_in[2];
  const float* proj_w = (const float*)d_in[3];
  const float* proj_b = (const float*)d_in[4];
  const int*   kptr   = (const int*)d_in[5];

  float* ws  = (float*)d_ws;
  const size_t sz = (size_t)Bn * Hn * Nn * Dn;   // 6291456 elements
  float* qbuf = ws;
  float* kbuf = ws + sz;
  float* vbuf = ws + 2*sz;
  float* att  = ws + 3*sz;                       // (B,N,C)
  float* outp = (float*)d_out;

  qkv_gemm<<<dim3(36*128), 256, 0, stream>>>(x, qkv_w, qkv_b, qbuf, kbuf, vbuf);
  attn_kernel<<<dim3(Bn*Hn*(Nn/8)), 512, 0, stream>>>(qbuf, kbuf, vbuf, kptr, att);
  proj_gemm<<<dim3(12*128), 256, 0, stream>>>(att, proj_w, proj_b, outp);
}